// Round 3
// baseline (362.640 us; speedup 1.0000x reference)
//
#include <hip/hip_runtime.h>

#define N_NODES 100000
#define N_EDGES 1600000
#define CAP 60         // per-node bucket capacity (Poisson(16): P(deg>60)~1e-16)
#define OVF_CAP 8192
#define GBLK 782       // ceil(100000/128) gemm blocks; also bin blocks (2048 edges)
#define NBIN 1563      // ceil(100000/64): bin = dst>>6 (one agg block per bin)
#define BINCAP2 1280   // Poisson(1024) + 8 sigma
#define FBLK 12500     // feat cvt blocks (float4: 3.2M threads)
#define ZROW 100000    // zero row index (padding gathers)
#define DEPTH 4        // gather pipeline depth (1KB slabs per wave)

typedef unsigned int uint;
typedef unsigned short ushort;
typedef __attribute__((ext_vector_type(8))) short short8;  // 8 bf16 (4 VGPRs)
typedef __attribute__((ext_vector_type(4))) float f32x4;   // 4 fp32

__device__ __forceinline__ ushort f2bf(float f) {
  uint x = __float_as_uint(f);
  x += 0x7fffu + ((x >> 16) & 1u);  // round-to-nearest-even
  return (ushort)(x >> 16);
}
__device__ __forceinline__ float bflo(uint u) {
  return __uint_as_float(u << 16);
}
__device__ __forceinline__ float bfhi(uint u) {
  return __uint_as_float(u & 0xffff0000u);
}
__device__ __forceinline__ f32x4 uplo(uint4 u) {
  return (f32x4){bflo(u.x), bfhi(u.x), bflo(u.y), bfhi(u.y)};
}
__device__ __forceinline__ f32x4 uphi(uint4 u) {
  return (f32x4){bflo(u.z), bfhi(u.z), bflo(u.w), bfhi(u.w)};
}

// async 16B/lane gather into LDS: global addr is PER-LANE, LDS dest is
// wave-uniform base + lane*16 (HW-defined layout).
__device__ __forceinline__ void gl_lds16(const uint4* g, uint4* l) {
  __builtin_amdgcn_global_load_lds(
      (const __attribute__((address_space(1))) uint*)g,
      (__attribute__((address_space(3))) uint*)l, 16, 0, 0);
}
__device__ __forceinline__ int wmax16(int v) {  // max over sub = lane>>4
  v = max(v, __shfl_xor(v, 16));
  v = max(v, __shfl_xor(v, 32));
  return v;
}
__device__ __forceinline__ int wmax8(int v) {  // max over sub = lane>>3
  v = max(v, __shfl_xor(v, 8));
  v = max(v, __shfl_xor(v, 16));
  v = max(v, __shfl_xor(v, 32));
  return v;
}

// ---------------- fused: edge binning + feat cvt + weight packing ----------
// Blocks [0,782): bin 2048 edges into dense per-bin (64-node) segments.
// gcursor is padded to one counter per 64B line (atomic contention fix).
// Blocks [782,13282): feat f32->bf16 (float4). Then 192 wp blocks + 1 zero-row.
__global__ __launch_bounds__(256) void k_pb(
    const int* __restrict__ src, const int* __restrict__ dst,
    const float* __restrict__ feat, const float* __restrict__ Ws0,
    const float* __restrict__ Wn0, const float* __restrict__ Ws1,
    const float* __restrict__ Wn1, uint* __restrict__ gcursor,
    uint* __restrict__ binbuf, int* __restrict__ ovf_cnt,
    int* __restrict__ ovf, uint* __restrict__ fbfu, ushort* __restrict__ wp0,
    ushort* __restrict__ wp1) {
  __shared__ uint hist[NBIN];  // counts, then bases (overwritten in place)
  int b = blockIdx.x;
  int tid = threadIdx.x;
  if (b < GBLK) {
    for (int i = tid; i < NBIN; i += 256) hist[i] = 0;
    __syncthreads();
    int e0 = b * 2048;
    uint val[8], bn[8], rk[8];
    int vld[8];
#pragma unroll
    for (int it = 0; it < 8; ++it) {
      int e = e0 + it * 256 + tid;
      vld[it] = (e < N_EDGES);
      if (vld[it]) {
        uint s = (uint)src[e];
        uint d = (uint)dst[e];
        bn[it] = d >> 6;
        rk[it] = atomicAdd(&hist[bn[it]], 1u);
        val[it] = s | ((d & 63u) << 17);
      }
    }
    __syncthreads();
    for (int i = tid; i < NBIN; i += 256) {
      uint h = hist[i];
      hist[i] = h ? atomicAdd(&gcursor[i * 16], h) : 0u;  // count -> base
    }
    __syncthreads();
#pragma unroll
    for (int it = 0; it < 8; ++it) {
      if (!vld[it]) continue;
      uint p = hist[bn[it]] + rk[it];
      if (p < BINCAP2) {
        binbuf[(size_t)bn[it] * BINCAP2 + p] = val[it];
      } else {  // ~never: segment overflow -> ovf, NOT counted (bit30=0)
        int o = atomicAdd(ovf_cnt, 1);
        if (o < OVF_CAP) {
          ovf[2 * o] = (int)(val[it] & 0x1FFFFu);
          ovf[2 * o + 1] = (int)(bn[it] * 64 + (val[it] >> 17));
        }
      }
    }
    return;
  }
  if (b < GBLK + FBLK) {  // feat conversion: float4 in, uint2 (4 bf16) out
    int i = (b - GBLK) * 256 + tid;
    float4 v = reinterpret_cast<const float4*>(feat)[i];
    uint2 o;
    o.x = (uint)f2bf(v.x) | ((uint)f2bf(v.y) << 16);
    o.y = (uint)f2bf(v.z) | ((uint)f2bf(v.w) << 16);
    reinterpret_cast<uint2*>(fbfu)[i] = o;
    return;
  }
  int wb = b - GBLK - FBLK;
  if (wb >= 192) {  // zero padding row fbf[100000]
    if (tid < 64) fbfu[ZROW * 64 + tid] = 0;
    return;
  }
  // B-frag layout (16x16x32 bf16): lane = 16q+c holds B[k=8q+j][n=16t+c].
  int idx = wb * 256 + tid;
  if (idx < 32768) {
    int k = idx >> 7, n = idx & 127;
    float v = (k < 128) ? Ws0[k * 128 + n] : Wn0[(k - 128) * 128 + n];
    int s = k >> 5, q = (k >> 3) & 3, j = k & 7;
    int t = n >> 4, c = n & 15;
    wp0[(((s * 8 + t) * 64) + (q * 16 + c)) * 8 + j] = f2bf(v);
  } else {
    int i2 = idx - 32768;
    int k = i2 >> 7, n = i2 & 127;
    float v = (n < 64) ? Wn1[k * 64 + n] : Ws1[k * 64 + (n - 64)];
    int s = k >> 5, q = (k >> 3) & 3, j = k & 7;
    int t = n >> 4, c = n & 15;
    wp1[(((s * 8 + t) * 64) + (q * 16 + c)) * 8 + j] = f2bf(v);
  }
}

// ---------------- layer-0 aggregation: global_load_lds ring pipeline ------
// Phase 1: scan own bin (~1024 edges) into ZROW-prefilled LDS buckets.
// Phase 2: per wave, 16 nodes in 4 groups of 4 (16 lanes x 256B row each).
// One slab = 1KB = 1 edge-slot for 4 nodes, DMA'd to LDS (no landing VGPRs).
// Ring of DEPTH=4 slabs, counted vmcnt(3): ~4KB in flight per wave.
__global__ __launch_bounds__(256) void k_agg0(
    const uint4* __restrict__ fbf4, const uint* __restrict__ binbuf,
    const uint* __restrict__ gcursor, int* __restrict__ ovf_cnt,
    int* __restrict__ ovf, uint4* __restrict__ agg4) {
  __shared__ __attribute__((aligned(16))) int lbkt[64 * CAP];
  __shared__ uint lcnt[64];
  __shared__ __attribute__((aligned(16))) uint4 gbuf[4 * DEPTH * 64];  // 16KB
  int bb = blockIdx.x;
  int tid = threadIdx.x;
  if (tid < 64) lcnt[tid] = 0;
  for (int i = tid; i < 64 * CAP; i += 256) lbkt[i] = ZROW;
  __syncthreads();
  int ne = min((int)gcursor[bb * 16], BINCAP2);
  for (int i = tid; i < ne; i += 256) {
    uint v = binbuf[(size_t)bb * BINCAP2 + i];
    int ldl = (int)(v >> 17);
    uint pos = atomicAdd(&lcnt[ldl], 1u);
    if (pos < CAP) {
      lbkt[ldl * CAP + pos] = (int)(v & 0x1FFFFu);
    } else {  // ~never: bucket spill -> ovf, counted (bit30=1)
      int o = atomicAdd(ovf_cnt, 1);
      if (o < OVF_CAP) {
        ovf[2 * o] = (int)(v & 0x1FFFFu);
        ovf[2 * o + 1] = (bb * 64 + ldl) | (1 << 30);
      }
    }
  }
  __syncthreads();

  int w = tid >> 6, lane = tid & 63;
  int sub = lane >> 4, li = lane & 15;
  uint4* slab = &gbuf[w * (DEPTH * 64)];
  int oc = min(*ovf_cnt, OVF_CAP);

  int kb0 = min((int)lcnt[w * 16 + sub], CAP);
  int kb1 = min((int)lcnt[w * 16 + 4 + sub], CAP);
  int kb2 = min((int)lcnt[w * 16 + 8 + sub], CAP);
  int kb3 = min((int)lcnt[w * 16 + 12 + sub], CAP);
  int mg0 = wmax16(kb0), mg1 = wmax16(kb1), mg2 = wmax16(kb2),
      mg3 = wmax16(kb3);
  int T = mg0 + mg1 + mg2 + mg3;
  auto MG = [&](int g) { return g == 0 ? mg0 : g == 1 ? mg1 : g == 2 ? mg2 : mg3; };

  f32x4 accA = (f32x4){0.f, 0.f, 0.f, 0.f};
  f32x4 accB = (f32x4){0.f, 0.f, 0.f, 0.f};
  auto FIN = [&](int g) {
    int nl = w * 16 + g * 4 + sub;
    int n = bb * 64 + nl;
    int c = (int)lcnt[nl];
    for (int i = 0; i < oc; ++i) {  // cold fallback
      int df = ovf[2 * i + 1];
      if ((df & 0x1FFFF) == n) {
        uint4 u = fbf4[(size_t)ovf[2 * i] * 16 + li];
        accA += uplo(u);
        accB += uphi(u);
        c += ((df >> 30) & 1) ^ 1;
      }
    }
    if (n < N_NODES) {
      float inv = 1.f / (float)max(c, 1);
      f32x4 rA = accA * inv, rB = accB * inv;
      uint4 o;
      o.x = (uint)f2bf(rA.x) | ((uint)f2bf(rA.y) << 16);
      o.y = (uint)f2bf(rA.z) | ((uint)f2bf(rA.w) << 16);
      o.z = (uint)f2bf(rB.x) | ((uint)f2bf(rB.y) << 16);
      o.w = (uint)f2bf(rB.z) | ((uint)f2bf(rB.w) << 16);
      agg4[(size_t)n * 16 + li] = o;
    }
    accA = (f32x4){0.f, 0.f, 0.f, 0.f};
    accB = (f32x4){0.f, 0.f, 0.f, 0.f};
  };
  auto ISSUE = [&](int gi, int ji, int slot) {
    int s = ZROW;
    if (gi < 4) s = lbkt[(w * 16 + gi * 4 + sub) * CAP + ji];
    gl_lds16(fbf4 + (size_t)s * 16 + li, slab + slot * 64);
  };

  int gi = 0, ji = 0;
  while (gi < 4 && MG(gi) == 0) gi++;
  for (int k = 0; k < DEPTH; ++k) {  // prime (dummies if T < DEPTH)
    ISSUE(gi, ji, k);
    if (gi < 4) {
      ji++;
      while (gi < 4 && ji >= MG(gi)) { gi++; ji = 0; }
    }
  }
  int gc = 0, jc = 0;
  while (gc < 4 && MG(gc) == 0) { FIN(gc); gc++; }
  for (int t = 0; t < T; ++t) {
    asm volatile("s_waitcnt vmcnt(3)" ::: "memory");
    __builtin_amdgcn_sched_barrier(0);
    uint4 u = slab[(t & (DEPTH - 1)) * 64 + lane];
    accA += uplo(u);
    accB += uphi(u);
    __builtin_amdgcn_sched_barrier(0);
    ISSUE(gi, ji, t & (DEPTH - 1));  // refill slot just consumed
    if (gi < 4) {
      ji++;
      while (gi < 4 && ji >= MG(gi)) { gi++; ji = 0; }
    }
    jc++;
    while (gc < 4 && jc >= MG(gc)) { FIN(gc); gc++; jc = 0; }
  }
  asm volatile("s_waitcnt vmcnt(0)" ::: "memory");  // drain trailing dummies
}

// ---------------- layer-0 MFMA GEMM: h = relu([feat|agg] @ Wp0 + b0) -------
__global__ __launch_bounds__(256) void k_gemm0(
    const ushort* __restrict__ fbf, const ushort* aggb,
    const uint4* __restrict__ wp0g, const float* __restrict__ b0,
    ushort* h) {
  __shared__ uint4 wlds[4096];  // 64KB
  int tid = threadIdx.x;
#pragma unroll
  for (int i = 0; i < 16; ++i) wlds[i * 256 + tid] = wp0g[i * 256 + tid];
  __syncthreads();
  const short8* wl8 = reinterpret_cast<const short8*>(wlds);

  int lane = tid & 63, w = tid >> 6;
  int quad = lane >> 4, lm = lane & 15;
  int mw = blockIdx.x * 128 + (w >> 1) * 64;
  int tgb = (w & 1) * 4;

  f32x4 acc[4][4];
#pragma unroll
  for (int rt = 0; rt < 4; ++rt)
#pragma unroll
    for (int ct = 0; ct < 4; ++ct) acc[rt][ct] = (f32x4){0.f, 0.f, 0.f, 0.f};
  short8 az = {0, 0, 0, 0, 0, 0, 0, 0};

#pragma unroll
  for (int s = 0; s < 8; ++s) {
    const ushort* bsrc = (s < 4) ? fbf : aggb;
    int koff = (s & 3) * 32 + quad * 8;
    short8 a[4];
#pragma unroll
    for (int rt = 0; rt < 4; ++rt) {
      int row = mw + rt * 16 + lm;
      a[rt] = (row < N_NODES)
                  ? *reinterpret_cast<const short8*>(bsrc + (size_t)row * 128 + koff)
                  : az;
    }
#pragma unroll
    for (int ct = 0; ct < 4; ++ct) {
      short8 b = wl8[(s * 8 + tgb + ct) * 64 + lane];
#pragma unroll
      for (int rt = 0; rt < 4; ++rt)
        acc[rt][ct] =
            __builtin_amdgcn_mfma_f32_16x16x32_bf16(a[rt], b, acc[rt][ct], 0, 0, 0);
    }
  }

  __syncthreads();  // all waves done reading aggb before h overwrites
  float bv[4];
#pragma unroll
  for (int ct = 0; ct < 4; ++ct) bv[ct] = b0[(tgb + ct) * 16 + lm];
#pragma unroll
  for (int rt = 0; rt < 4; ++rt)
#pragma unroll
    for (int ct = 0; ct < 4; ++ct)
#pragma unroll
      for (int i = 0; i < 4; ++i) {
        int row = mw + rt * 16 + quad * 4 + i;
        if (row < N_NODES) {
          int col = (tgb + ct) * 16 + lm;
          h[(size_t)row * 128 + col] = f2bf(fmaxf(acc[rt][ct][i] + bv[ct], 0.f));
        }
      }
}

// ---------------- fused layer-1 MFMA GEMM: [hw | sout] = h @ Wp1 -----------
__global__ __launch_bounds__(256) void k_gemm1(
    const ushort* __restrict__ h, const uint4* __restrict__ wp1g,
    const float* __restrict__ b1, ushort* __restrict__ hw,
    float* __restrict__ out) {
  __shared__ uint4 wlds[2048];  // 32KB
  int tid = threadIdx.x;
  if (blockIdx.x == 0 && tid < 8)  // zero padding row hw[100000]
    reinterpret_cast<uint4*>(hw)[ZROW * 8 + tid] = make_uint4(0, 0, 0, 0);
#pragma unroll
  for (int i = 0; i < 8; ++i) wlds[i * 256 + tid] = wp1g[i * 256 + tid];
  __syncthreads();
  const short8* wl8 = reinterpret_cast<const short8*>(wlds);

  int lane = tid & 63, w = tid >> 6;
  int quad = lane >> 4, lm = lane & 15;
  int mw = blockIdx.x * 128 + (w >> 1) * 64;
  int tgb = (w & 1) * 4;

  f32x4 acc[4][4];
#pragma unroll
  for (int rt = 0; rt < 4; ++rt)
#pragma unroll
    for (int ct = 0; ct < 4; ++ct) acc[rt][ct] = (f32x4){0.f, 0.f, 0.f, 0.f};
  short8 az = {0, 0, 0, 0, 0, 0, 0, 0};

#pragma unroll
  for (int s = 0; s < 4; ++s) {
    int koff = s * 32 + quad * 8;
    short8 a[4];
#pragma unroll
    for (int rt = 0; rt < 4; ++rt) {
      int row = mw + rt * 16 + lm;
      a[rt] = (row < N_NODES)
                  ? *reinterpret_cast<const short8*>(h + (size_t)row * 128 + koff)
                  : az;
    }
#pragma unroll
    for (int ct = 0; ct < 4; ++ct) {
      short8 b = wl8[(s * 8 + tgb + ct) * 64 + lane];
#pragma unroll
      for (int rt = 0; rt < 4; ++rt)
        acc[rt][ct] =
            __builtin_amdgcn_mfma_f32_16x16x32_bf16(a[rt], b, acc[rt][ct], 0, 0, 0);
    }
  }

  if ((w & 1) == 0) {  // cols 0..63 -> hw = h@Wn1 (bf16)
#pragma unroll
    for (int rt = 0; rt < 4; ++rt)
#pragma unroll
      for (int ct = 0; ct < 4; ++ct)
#pragma unroll
        for (int i = 0; i < 4; ++i) {
          int row = mw + rt * 16 + quad * 4 + i;
          if (row < N_NODES)
            hw[(size_t)row * 64 + ct * 16 + lm] = f2bf(acc[rt][ct][i]);
        }
  } else {  // cols 64..127 -> out = h@Ws1 + b1 (f32)
    float bv[4];
#pragma unroll
    for (int ct = 0; ct < 4; ++ct) bv[ct] = b1[ct * 16 + lm];
#pragma unroll
    for (int rt = 0; rt < 4; ++rt)
#pragma unroll
      for (int ct = 0; ct < 4; ++ct)
#pragma unroll
        for (int i = 0; i < 4; ++i) {
          int row = mw + rt * 16 + quad * 4 + i;
          if (row < N_NODES)
            out[(size_t)row * 64 + ct * 16 + lm] = acc[rt][ct][i] + bv[ct];
        }
  }
}

// ---------------- layer-1 aggregation: same ring pipeline, 128B rows -------
// Slab = 1KB = 1 edge-slot for 8 nodes (8 lanes x 128B row). Per wave:
// 16 nodes in 2 groups of 8.
__global__ __launch_bounds__(256) void k_agg1(
    const uint4* __restrict__ hw4, const uint* __restrict__ binbuf,
    const uint* __restrict__ gcursor, int* __restrict__ ovf_cnt,
    int* __restrict__ ovf, float* __restrict__ out) {
  __shared__ __attribute__((aligned(16))) int lbkt[64 * CAP];
  __shared__ uint lcnt[64];
  __shared__ __attribute__((aligned(16))) uint4 gbuf[4 * DEPTH * 64];  // 16KB
  int bb = blockIdx.x;
  int tid = threadIdx.x;
  if (tid < 64) lcnt[tid] = 0;
  for (int i = tid; i < 64 * CAP; i += 256) lbkt[i] = ZROW;
  __syncthreads();
  int ne = min((int)gcursor[bb * 16], BINCAP2);
  for (int i = tid; i < ne; i += 256) {
    uint v = binbuf[(size_t)bb * BINCAP2 + i];
    int ldl = (int)(v >> 17);
    uint pos = atomicAdd(&lcnt[ldl], 1u);
    if (pos < CAP) lbkt[ldl * CAP + pos] = (int)(v & 0x1FFFFu);
    // bucket spill already recorded in ovf by k_agg0's pass (bit30=1)
  }
  __syncthreads();

  int w = tid >> 6, lane = tid & 63;
  int sub = lane >> 3, li = lane & 7;
  uint4* slab = &gbuf[w * (DEPTH * 64)];
  int oc = min(*ovf_cnt, OVF_CAP);

  int kb0 = min((int)lcnt[w * 16 + sub], CAP);
  int kb1 = min((int)lcnt[w * 16 + 8 + sub], CAP);
  int mg0 = wmax8(kb0), mg1 = wmax8(kb1);
  int T = mg0 + mg1;
  auto MG = [&](int g) { return g == 0 ? mg0 : mg1; };

  f32x4 accA = (f32x4){0.f, 0.f, 0.f, 0.f};
  f32x4 accB = (f32x4){0.f, 0.f, 0.f, 0.f};
  auto FIN = [&](int g) {
    int nl = w * 16 + g * 8 + sub;
    int n = bb * 64 + nl;
    int c = (int)lcnt[nl];
    for (int i = 0; i < oc; ++i) {  // cold fallback
      int df = ovf[2 * i + 1];
      if ((df & 0x1FFFF) == n) {
        uint4 u = hw4[(size_t)ovf[2 * i] * 8 + li];
        accA += uplo(u);
        accB += uphi(u);
        c += ((df >> 30) & 1) ^ 1;
      }
    }
    if (n < N_NODES) {
      float inv = 1.f / (float)max(c, 1);
      float* op = out + (size_t)n * 64 + li * 8;
      float4 c0 = *reinterpret_cast<float4*>(op);
      float4 c1 = *reinterpret_cast<float4*>(op + 4);
      c0.x += accA.x * inv;
      c0.y += accA.y * inv;
      c0.z += accA.z * inv;
      c0.w += accA.w * inv;
      c1.x += accB.x * inv;
      c1.y += accB.y * inv;
      c1.z += accB.z * inv;
      c1.w += accB.w * inv;
      *reinterpret_cast<float4*>(op) = c0;
      *reinterpret_cast<float4*>(op + 4) = c1;
    }
    accA = (f32x4){0.f, 0.f, 0.f, 0.f};
    accB = (f32x4){0.f, 0.f, 0.f, 0.f};
  };
  auto ISSUE = [&](int gi, int ji, int slot) {
    int s = ZROW;
    if (gi < 2) s = lbkt[(w * 16 + gi * 8 + sub) * CAP + ji];
    gl_lds16(hw4 + (size_t)s * 8 + li, slab + slot * 64);
  };

  int gi = 0, ji = 0;
  while (gi < 2 && MG(gi) == 0) gi++;
  for (int k = 0; k < DEPTH; ++k) {  // prime
    ISSUE(gi, ji, k);
    if (gi < 2) {
      ji++;
      while (gi < 2 && ji >= MG(gi)) { gi++; ji = 0; }
    }
  }
  int gc = 0, jc = 0;
  while (gc < 2 && MG(gc) == 0) { FIN(gc); gc++; }
  for (int t = 0; t < T; ++t) {
    asm volatile("s_waitcnt vmcnt(3)" ::: "memory");
    __builtin_amdgcn_sched_barrier(0);
    uint4 u = slab[(t & (DEPTH - 1)) * 64 + lane];
    accA += uplo(u);
    accB += uphi(u);
    __builtin_amdgcn_sched_barrier(0);
    ISSUE(gi, ji, t & (DEPTH - 1));
    if (gi < 2) {
      ji++;
      while (gi < 2 && ji >= MG(gi)) { gi++; ji = 0; }
    }
    jc++;
    while (gc < 2 && jc >= MG(gc)) { FIN(gc); gc++; jc = 0; }
  }
  asm volatile("s_waitcnt vmcnt(0)" ::: "memory");
}

extern "C" void kernel_launch(void* const* d_in, const int* in_sizes, int n_in,
                              void* d_out, int out_size, void* d_ws,
                              size_t ws_size, hipStream_t stream) {
  const float* feat = (const float*)d_in[0];
  const int* src = (const int*)d_in[1];
  const int* dst = (const int*)d_in[2];
  const float* Ws0 = (const float*)d_in[3];
  const float* Wn0 = (const float*)d_in[4];
  const float* b0 = (const float*)d_in[5];
  const float* Ws1 = (const float*)d_in[6];
  const float* Wn1 = (const float*)d_in[7];
  const float* b1 = (const float*)d_in[8];
  char* ws = (char*)d_ws;

  // Workspace (59.5 MB <= 77.2 MB proven):
  //   hbuf    @ 0          : 25,600,000  (bf16 agg0, then h)
  //   ovf_cnt @ 25,600,000 :         64
  //   gcursor @ 25,600,064 :    100,032  (1563 cursors, 64B-strided)
  //   ovf     @ 25,700,096 :     65,536
  //   binbuf  @ 25,765,632 :  8,002,560  (1563 x 1280 packed edges)
  //   feat_bf @ 33,768,192 : 25,600,256  (bf16 + zero row; hw reuses after gemm0)
  //   wp0     @ 59,368,448 :     65,536
  //   wp1     @ 59,433,984 :     32,768
  ushort* hbuf = (ushort*)(ws);
  int* ovf_cnt = (int*)(ws + 25600000);
  uint* gcursor = (uint*)(ws + 25600064);
  int* ovf = (int*)(ws + 25700096);
  uint* binbuf = (uint*)(ws + 25765632);
  ushort* fbf = (ushort*)(ws + 33768192);
  ushort* hw = (ushort*)(ws + 33768192);  // reuses feat_bf post-gemm0
  ushort* wp0 = (ushort*)(ws + 59368448);
  ushort* wp1 = (ushort*)(ws + 59433984);
  float* out = (float*)d_out;

  hipMemsetAsync(ws + 25600000, 0, 100096, stream);  // ovf_cnt + gcursor
  k_pb<<<GBLK + FBLK + 193, 256, 0, stream>>>(src, dst, feat, Ws0, Wn0, Ws1,
                                              Wn1, gcursor, binbuf, ovf_cnt,
                                              ovf, (uint*)fbf, wp0, wp1);
  k_agg0<<<NBIN, 256, 0, stream>>>((const uint4*)fbf, binbuf, gcursor, ovf_cnt,
                                   ovf, (uint4*)hbuf);
  k_gemm0<<<GBLK, 256, 0, stream>>>(fbf, hbuf, (const uint4*)wp0, b0, hbuf);
  k_gemm1<<<GBLK, 256, 0, stream>>>(hbuf, (const uint4*)wp1, b1, hw, out);
  k_agg1<<<NBIN, 256, 0, stream>>>((const uint4*)hw, binbuf, gcursor, ovf_cnt,
                                   ovf, out);
}

// Round 4
// 301.064 us; speedup vs baseline: 1.2045x; 1.2045x over previous
//
#include <hip/hip_runtime.h>

#define N_NODES 100000
#define N_EDGES 1600000
#define CAP 60         // per-node bucket capacity, mult. of 12 (Poisson(16): P(deg>60)~1e-16)
#define OVF_CAP 8192
#define GBLK 782       // ceil(100000/128) gemm blocks; also bin blocks (2048 edges)
#define NBIN 1563      // ceil(100000/64): bin = dst>>6 (one agg block per bin)
#define BINCAP2 1280   // Poisson(1024) + 8 sigma
#define FBLK 12500     // feat cvt blocks (float4: 3.2M threads)
#define ZROW 100000    // zero row index (padding gathers)

typedef unsigned int uint;
typedef unsigned short ushort;
typedef __attribute__((ext_vector_type(8))) short short8;  // 8 bf16 (4 VGPRs)
typedef __attribute__((ext_vector_type(4))) float f32x4;   // 4 fp32

__device__ __forceinline__ ushort f2bf(float f) {
  uint x = __float_as_uint(f);
  x += 0x7fffu + ((x >> 16) & 1u);  // round-to-nearest-even
  return (ushort)(x >> 16);
}
__device__ __forceinline__ float bflo(uint u) {
  return __uint_as_float(u << 16);
}
__device__ __forceinline__ float bfhi(uint u) {
  return __uint_as_float(u & 0xffff0000u);
}
// low/high 4 floats of a uint4 (8 bf16)
__device__ __forceinline__ f32x4 uplo(uint4 u) {
  return (f32x4){bflo(u.x), bfhi(u.x), bflo(u.y), bfhi(u.y)};
}
__device__ __forceinline__ f32x4 uphi(uint4 u) {
  return (f32x4){bflo(u.z), bfhi(u.z), bflo(u.w), bfhi(u.w)};
}

// ---------------- fused: edge binning + feat cvt + weight packing ----------
// Blocks [0,782): bin 2048 edges each into dense per-bin (64-node) segments
// (LDS histogram -> global cursor atomics -> packed (src | dlow<<17) writes).
// gcursor is padded to one counter per 64B line (atomic contention fix).
// Blocks [782,13282): feat f32->bf16 (float4 loads). Then 192 blocks MFMA
// B-frag weight packing + 1 block zeroing padding rows fbf/hw[100000].
__global__ __launch_bounds__(256) void k_pb(
    const int* __restrict__ src, const int* __restrict__ dst,
    const float* __restrict__ feat, const float* __restrict__ Ws0,
    const float* __restrict__ Wn0, const float* __restrict__ Ws1,
    const float* __restrict__ Wn1, uint* __restrict__ gcursor,
    uint* __restrict__ binbuf, int* __restrict__ ovf_cnt,
    int* __restrict__ ovf, uint* __restrict__ fbfu, uint* __restrict__ hwu,
    ushort* __restrict__ wp0, ushort* __restrict__ wp1) {
  __shared__ uint hist[NBIN];  // counts, then bases (overwritten in place)
  int b = blockIdx.x;
  int tid = threadIdx.x;
  if (b < GBLK) {
    for (int i = tid; i < NBIN; i += 256) hist[i] = 0;
    __syncthreads();
    int e0 = b * 2048;
    uint val[8], bn[8], rk[8];
    int vld[8];
#pragma unroll
    for (int it = 0; it < 8; ++it) {
      int e = e0 + it * 256 + tid;
      vld[it] = (e < N_EDGES);
      if (vld[it]) {
        uint s = (uint)src[e];
        uint d = (uint)dst[e];
        bn[it] = d >> 6;
        rk[it] = atomicAdd(&hist[bn[it]], 1u);
        val[it] = s | ((d & 63u) << 17);
      }
    }
    __syncthreads();
    for (int i = tid; i < NBIN; i += 256) {
      uint h = hist[i];
      hist[i] = h ? atomicAdd(&gcursor[i * 16], h) : 0u;  // count -> base
    }
    __syncthreads();
#pragma unroll
    for (int it = 0; it < 8; ++it) {
      if (!vld[it]) continue;
      uint p = hist[bn[it]] + rk[it];
      if (p < BINCAP2) {
        binbuf[(size_t)bn[it] * BINCAP2 + p] = val[it];
      } else {  // ~never: segment overflow -> ovf, NOT counted (bit30=0)
        int o = atomicAdd(ovf_cnt, 1);
        if (o < OVF_CAP) {
          ovf[2 * o] = (int)(val[it] & 0x1FFFFu);
          ovf[2 * o + 1] = (int)(bn[it] * 64 + (val[it] >> 17));
        }
      }
    }
    return;
  }
  if (b < GBLK + FBLK) {  // feat conversion: float4 in, uint2 (4 bf16) out
    int i = (b - GBLK) * 256 + tid;
    float4 v = reinterpret_cast<const float4*>(feat)[i];
    uint2 o;
    o.x = (uint)f2bf(v.x) | ((uint)f2bf(v.y) << 16);
    o.y = (uint)f2bf(v.z) | ((uint)f2bf(v.w) << 16);
    reinterpret_cast<uint2*>(fbfu)[i] = o;
    return;
  }
  int wb = b - GBLK - FBLK;
  if (wb >= 192) {  // zero padding rows fbf[100000], hw[100000]
    if (tid < 64) fbfu[ZROW * 64 + tid] = 0;
    else if (tid < 96) hwu[ZROW * 32 + (tid - 64)] = 0;
    return;
  }
  // B-frag layout (16x16x32 bf16): lane = 16q+c holds B[k=8q+j][n=16t+c].
  int idx = wb * 256 + tid;  // 49152 = 32768 + 16384
  if (idx < 32768) {
    int k = idx >> 7, n = idx & 127;
    float v = (k < 128) ? Ws0[k * 128 + n] : Wn0[(k - 128) * 128 + n];
    int s = k >> 5, q = (k >> 3) & 3, j = k & 7;
    int t = n >> 4, c = n & 15;
    wp0[(((s * 8 + t) * 64) + (q * 16 + c)) * 8 + j] = f2bf(v);
  } else {
    int i2 = idx - 32768;
    int k = i2 >> 7, n = i2 & 127;
    float v = (n < 64) ? Wn1[k * 64 + n] : Ws1[k * 64 + (n - 64)];
    int s = k >> 5, q = (k >> 3) & 3, j = k & 7;
    int t = n >> 4, c = n & 15;
    wp1[(((s * 8 + t) * 64) + (q * 16 + c)) * 8 + j] = f2bf(v);
  }
}

// ---------------- layer-0 aggregation (LDS bucket): 64 nodes/block ---------
// Phase 1: scan own bin's binbuf segment (~1024 edges, no filtering),
// scatter src ids into a 15KB LDS bucket pre-filled with ZROW.
// Phase 2: 16 lanes per node own the 256B row; 12-deep unconditional gather
// batches (12 dwordx4 in flight/lane, tail lanes hit the zero row).
__global__ __launch_bounds__(256) void k_agg0(
    const uint4* __restrict__ fbf4, const uint* __restrict__ binbuf,
    const uint* __restrict__ gcursor, int* __restrict__ ovf_cnt,
    int* __restrict__ ovf, uint4* __restrict__ agg4) {
  __shared__ __attribute__((aligned(16))) int lbkt[64 * CAP];
  __shared__ uint lcnt[64];
  int bb = blockIdx.x;
  int tid = threadIdx.x;
  if (tid < 64) lcnt[tid] = 0;
#pragma unroll
  for (int i = tid; i < 64 * CAP; i += 256) lbkt[i] = ZROW;
  __syncthreads();
  int ne = min((int)gcursor[bb * 16], BINCAP2);
  for (int i = tid; i < ne; i += 256) {
    uint v = binbuf[(size_t)bb * BINCAP2 + i];
    int ldl = (int)(v >> 17);
    uint pos = atomicAdd(&lcnt[ldl], 1u);
    if (pos < CAP) {
      lbkt[ldl * CAP + pos] = (int)(v & 0x1FFFFu);
    } else {  // ~never: bucket spill -> ovf, already counted (bit30=1)
      int o = atomicAdd(ovf_cnt, 1);
      if (o < OVF_CAP) {
        ovf[2 * o] = (int)(v & 0x1FFFFu);
        ovf[2 * o + 1] = (bb * 64 + ldl) | (1 << 30);
      }
    }
  }
  __syncthreads();
  int g = tid >> 4, li = tid & 15;
  const int4* lb4 = reinterpret_cast<const int4*>(lbkt);
  int oc = min(*ovf_cnt, OVF_CAP);
#pragma unroll
  for (int p = 0; p < 4; ++p) {
    int nl = p * 16 + g;
    int n = bb * 64 + nl;
    int c = (int)lcnt[nl];
    int kb = min(c, CAP);
    f32x4 accA = (f32x4){0.f, 0.f, 0.f, 0.f};
    f32x4 accB = (f32x4){0.f, 0.f, 0.f, 0.f};
    for (int j = 0; j < kb; j += 12) {
      int4 ia = lb4[nl * 15 + (j >> 2)];
      int4 ib = lb4[nl * 15 + (j >> 2) + 1];
      int4 ic = lb4[nl * 15 + (j >> 2) + 2];
      uint4 u0 = fbf4[(size_t)ia.x * 16 + li];
      uint4 u1 = fbf4[(size_t)ia.y * 16 + li];
      uint4 u2 = fbf4[(size_t)ia.z * 16 + li];
      uint4 u3 = fbf4[(size_t)ia.w * 16 + li];
      uint4 u4 = fbf4[(size_t)ib.x * 16 + li];
      uint4 u5 = fbf4[(size_t)ib.y * 16 + li];
      uint4 u6 = fbf4[(size_t)ib.z * 16 + li];
      uint4 u7 = fbf4[(size_t)ib.w * 16 + li];
      uint4 u8 = fbf4[(size_t)ic.x * 16 + li];
      uint4 u9 = fbf4[(size_t)ic.y * 16 + li];
      uint4 ua = fbf4[(size_t)ic.z * 16 + li];
      uint4 ub = fbf4[(size_t)ic.w * 16 + li];
      accA += uplo(u0); accB += uphi(u0);
      accA += uplo(u1); accB += uphi(u1);
      accA += uplo(u2); accB += uphi(u2);
      accA += uplo(u3); accB += uphi(u3);
      accA += uplo(u4); accB += uphi(u4);
      accA += uplo(u5); accB += uphi(u5);
      accA += uplo(u6); accB += uphi(u6);
      accA += uplo(u7); accB += uphi(u7);
      accA += uplo(u8); accB += uphi(u8);
      accA += uplo(u9); accB += uphi(u9);
      accA += uplo(ua); accB += uphi(ua);
      accA += uplo(ub); accB += uphi(ub);
    }
    for (int i = 0; i < oc; ++i) {  // cold fallback path
      int df = ovf[2 * i + 1];
      if ((df & 0x1FFFF) == n) {
        uint4 u = fbf4[(size_t)ovf[2 * i] * 16 + li];
        accA += uplo(u);
        accB += uphi(u);
        c += ((df >> 30) & 1) ^ 1;
      }
    }
    float inv = 1.f / (float)max(c, 1);
    accA *= inv;
    accB *= inv;
    if (n < N_NODES) {
      uint4 o;
      o.x = (uint)f2bf(accA.x) | ((uint)f2bf(accA.y) << 16);
      o.y = (uint)f2bf(accA.z) | ((uint)f2bf(accA.w) << 16);
      o.z = (uint)f2bf(accB.x) | ((uint)f2bf(accB.y) << 16);
      o.w = (uint)f2bf(accB.z) | ((uint)f2bf(accB.w) << 16);
      agg4[(size_t)n * 16 + li] = o;
    }
  }
}

// ---------------- fused MFMA GEMM: h-tile in LDS, no h round-trip ----------
// Phase 1: h = relu([fbf|agg] @ Wp0 + b0) -> 32KB LDS tile (col-XOR swizzle).
// Phase 2: [hw | out] = h_tile @ Wp1. B-frags read directly from global
// (wp0/wp1 = 96KB, L2-hot across all blocks) -> LDS stays 32KB, 5 blocks/CU.
__global__ __launch_bounds__(256) void k_gemm(
    const ushort* __restrict__ fbf, const ushort* __restrict__ aggb,
    const short8* __restrict__ wp0f, const short8* __restrict__ wp1f,
    const float* __restrict__ b0, const float* __restrict__ b1,
    ushort* __restrict__ hw, float* __restrict__ out) {
  __shared__ ushort htile[128 * 128];  // 32KB; idx = r*128 + (c ^ ((r&15)*8))
  int tid = threadIdx.x;
  int lane = tid & 63, w = tid >> 6;
  int quad = lane >> 4, lm = lane & 15;
  int rl0 = (w >> 1) * 64;            // block-local row base of this wave
  int mw = blockIdx.x * 128 + rl0;
  int tgb = (w & 1) * 4;

  f32x4 acc[4][4];
#pragma unroll
  for (int rt = 0; rt < 4; ++rt)
#pragma unroll
    for (int ct = 0; ct < 4; ++ct) acc[rt][ct] = (f32x4){0.f, 0.f, 0.f, 0.f};
  short8 az = {0, 0, 0, 0, 0, 0, 0, 0};

#pragma unroll
  for (int s = 0; s < 8; ++s) {  // K=256 over [fbf | agg]
    const ushort* bsrc = (s < 4) ? fbf : aggb;
    int koff = (s & 3) * 32 + quad * 8;
    short8 a[4];
#pragma unroll
    for (int rt = 0; rt < 4; ++rt) {
      int row = mw + rt * 16 + lm;
      a[rt] = (row < N_NODES)
                  ? *reinterpret_cast<const short8*>(bsrc + (size_t)row * 128 + koff)
                  : az;
    }
#pragma unroll
    for (int ct = 0; ct < 4; ++ct) {
      short8 b = wp0f[(s * 8 + tgb + ct) * 64 + lane];
#pragma unroll
      for (int rt = 0; rt < 4; ++rt)
        acc[rt][ct] =
            __builtin_amdgcn_mfma_f32_16x16x32_bf16(a[rt], b, acc[rt][ct], 0, 0, 0);
    }
  }

  {  // epilogue 1 -> LDS h-tile (bias + relu + bf16); tail rows zeroed
    float bv[4];
#pragma unroll
    for (int ct = 0; ct < 4; ++ct) bv[ct] = b0[(tgb + ct) * 16 + lm];
#pragma unroll
    for (int rt = 0; rt < 4; ++rt)
#pragma unroll
      for (int ct = 0; ct < 4; ++ct)
#pragma unroll
        for (int i = 0; i < 4; ++i) {
          int r = rl0 + rt * 16 + quad * 4 + i;
          float v = (blockIdx.x * 128 + r < N_NODES)
                        ? fmaxf(acc[rt][ct][i] + bv[ct], 0.f)
                        : 0.f;
          int col = (tgb + ct) * 16 + lm;
          htile[r * 128 + (col ^ ((r & 15) * 8))] = f2bf(v);
        }
  }
  __syncthreads();

#pragma unroll
  for (int rt = 0; rt < 4; ++rt)
#pragma unroll
    for (int ct = 0; ct < 4; ++ct) acc[rt][ct] = (f32x4){0.f, 0.f, 0.f, 0.f};

#pragma unroll
  for (int s = 0; s < 4; ++s) {  // K=128 from h-tile
    int koff = s * 32 + quad * 8;
    short8 a[4];
#pragma unroll
    for (int rt = 0; rt < 4; ++rt) {
      int r = rl0 + rt * 16 + lm;
      a[rt] = *reinterpret_cast<const short8*>(
          &htile[r * 128 + (koff ^ ((r & 15) * 8))]);
    }
#pragma unroll
    for (int ct = 0; ct < 4; ++ct) {
      short8 b = wp1f[(s * 8 + tgb + ct) * 64 + lane];
#pragma unroll
      for (int rt = 0; rt < 4; ++rt)
        acc[rt][ct] =
            __builtin_amdgcn_mfma_f32_16x16x32_bf16(a[rt], b, acc[rt][ct], 0, 0, 0);
    }
  }

  if ((w & 1) == 0) {  // cols 0..63 -> hw = h@Wn1 (bf16)
#pragma unroll
    for (int rt = 0; rt < 4; ++rt)
#pragma unroll
      for (int ct = 0; ct < 4; ++ct)
#pragma unroll
        for (int i = 0; i < 4; ++i) {
          int row = mw + rt * 16 + quad * 4 + i;
          if (row < N_NODES)
            hw[(size_t)row * 64 + ct * 16 + lm] = f2bf(acc[rt][ct][i]);
        }
  } else {  // cols 64..127 -> out = h@Ws1 + b1 (f32)
    float bv[4];
#pragma unroll
    for (int ct = 0; ct < 4; ++ct) bv[ct] = b1[ct * 16 + lm];
#pragma unroll
    for (int rt = 0; rt < 4; ++rt)
#pragma unroll
      for (int ct = 0; ct < 4; ++ct)
#pragma unroll
        for (int i = 0; i < 4; ++i) {
          int row = mw + rt * 16 + quad * 4 + i;
          if (row < N_NODES)
            out[(size_t)row * 64 + ct * 16 + lm] = acc[rt][ct][i] + bv[ct];
        }
  }
}

// ---------------- layer-1 aggregation (LDS bucket): out[n] += mean ---------
// Same structure as k_agg0; 8 lanes per node own the 128B hw row.
__global__ __launch_bounds__(256) void k_agg1(
    const uint4* __restrict__ hw4, const uint* __restrict__ binbuf,
    const uint* __restrict__ gcursor, int* __restrict__ ovf_cnt,
    int* __restrict__ ovf, float* __restrict__ out) {
  __shared__ __attribute__((aligned(16))) int lbkt[64 * CAP];
  __shared__ uint lcnt[64];
  int bb = blockIdx.x;
  int tid = threadIdx.x;
  if (tid < 64) lcnt[tid] = 0;
#pragma unroll
  for (int i = tid; i < 64 * CAP; i += 256) lbkt[i] = ZROW;
  __syncthreads();
  int ne = min((int)gcursor[bb * 16], BINCAP2);
  for (int i = tid; i < ne; i += 256) {
    uint v = binbuf[(size_t)bb * BINCAP2 + i];
    int ldl = (int)(v >> 17);
    uint pos = atomicAdd(&lcnt[ldl], 1u);
    if (pos < CAP) lbkt[ldl * CAP + pos] = (int)(v & 0x1FFFFu);
    // bucket spill already recorded in ovf by k_agg0's pass (bit30=1)
  }
  __syncthreads();
  int g = tid >> 3, li = tid & 7;
  const int4* lb4 = reinterpret_cast<const int4*>(lbkt);
  int oc = min(*ovf_cnt, OVF_CAP);
#pragma unroll
  for (int p = 0; p < 2; ++p) {
    int nl = p * 32 + g;
    int n = bb * 64 + nl;
    int c = (int)lcnt[nl];
    int kb = min(c, CAP);
    f32x4 accA = (f32x4){0.f, 0.f, 0.f, 0.f};
    f32x4 accB = (f32x4){0.f, 0.f, 0.f, 0.f};
    for (int j = 0; j < kb; j += 12) {
      int4 ia = lb4[nl * 15 + (j >> 2)];
      int4 ib = lb4[nl * 15 + (j >> 2) + 1];
      int4 ic = lb4[nl * 15 + (j >> 2) + 2];
      uint4 u0 = hw4[(size_t)ia.x * 8 + li];
      uint4 u1 = hw4[(size_t)ia.y * 8 + li];
      uint4 u2 = hw4[(size_t)ia.z * 8 + li];
      uint4 u3 = hw4[(size_t)ia.w * 8 + li];
      uint4 u4 = hw4[(size_t)ib.x * 8 + li];
      uint4 u5 = hw4[(size_t)ib.y * 8 + li];
      uint4 u6 = hw4[(size_t)ib.z * 8 + li];
      uint4 u7 = hw4[(size_t)ib.w * 8 + li];
      uint4 u8 = hw4[(size_t)ic.x * 8 + li];
      uint4 u9 = hw4[(size_t)ic.y * 8 + li];
      uint4 ua = hw4[(size_t)ic.z * 8 + li];
      uint4 ub = hw4[(size_t)ic.w * 8 + li];
      accA += uplo(u0); accB += uphi(u0);
      accA += uplo(u1); accB += uphi(u1);
      accA += uplo(u2); accB += uphi(u2);
      accA += uplo(u3); accB += uphi(u3);
      accA += uplo(u4); accB += uphi(u4);
      accA += uplo(u5); accB += uphi(u5);
      accA += uplo(u6); accB += uphi(u6);
      accA += uplo(u7); accB += uphi(u7);
      accA += uplo(u8); accB += uphi(u8);
      accA += uplo(u9); accB += uphi(u9);
      accA += uplo(ua); accB += uphi(ua);
      accA += uplo(ub); accB += uphi(ub);
    }
    for (int i = 0; i < oc; ++i) {  // cold fallback path
      int df = ovf[2 * i + 1];
      if ((df & 0x1FFFF) == n) {
        uint4 u = hw4[(size_t)ovf[2 * i] * 8 + li];
        accA += uplo(u);
        accB += uphi(u);
        c += ((df >> 30) & 1) ^ 1;
      }
    }
    if (n < N_NODES) {
      float inv = 1.f / (float)max(c, 1);
      float* op = out + (size_t)n * 64 + li * 8;
      float4 c0 = *reinterpret_cast<float4*>(op);
      float4 c1 = *reinterpret_cast<float4*>(op + 4);
      c0.x += accA.x * inv;
      c0.y += accA.y * inv;
      c0.z += accA.z * inv;
      c0.w += accA.w * inv;
      c1.x += accB.x * inv;
      c1.y += accB.y * inv;
      c1.z += accB.z * inv;
      c1.w += accB.w * inv;
      *reinterpret_cast<float4*>(op) = c0;
      *reinterpret_cast<float4*>(op + 4) = c1;
    }
  }
}

extern "C" void kernel_launch(void* const* d_in, const int* in_sizes, int n_in,
                              void* d_out, int out_size, void* d_ws,
                              size_t ws_size, hipStream_t stream) {
  const float* feat = (const float*)d_in[0];
  const int* src = (const int*)d_in[1];
  const int* dst = (const int*)d_in[2];
  const float* Ws0 = (const float*)d_in[3];
  const float* Wn0 = (const float*)d_in[4];
  const float* b0 = (const float*)d_in[5];
  const float* Ws1 = (const float*)d_in[6];
  const float* Wn1 = (const float*)d_in[7];
  const float* b1 = (const float*)d_in[8];
  char* ws = (char*)d_ws;

  // Workspace (72.3 MB <= 77.2 MB proven):
  //   hbuf    @ 0          : 25,600,000  (bf16 agg0 out, read by k_gemm ph1)
  //   ovf_cnt @ 25,600,000 :         64
  //   gcursor @ 25,600,064 :    100,032  (1563 cursors, 64B-strided)
  //   ovf     @ 25,700,096 :     65,536
  //   binbuf  @ 25,765,632 :  8,002,560  (1563 x 1280 packed edges)
  //   feat_bf @ 33,768,192 : 25,600,256  (bf16 + zero row)
  //   hw      @ 59,368,448 : 12,800,128  (bf16 h@Wn1 + zero row)
  //   wp0     @ 72,168,576 :     65,536
  //   wp1     @ 72,234,112 :     32,768
  ushort* hbuf = (ushort*)(ws);
  int* ovf_cnt = (int*)(ws + 25600000);
  uint* gcursor = (uint*)(ws + 25600064);
  int* ovf = (int*)(ws + 25700096);
  uint* binbuf = (uint*)(ws + 25765632);
  ushort* fbf = (ushort*)(ws + 33768192);
  ushort* hw = (ushort*)(ws + 59368448);
  ushort* wp0 = (ushort*)(ws + 72168576);
  ushort* wp1 = (ushort*)(ws + 72234112);
  float* out = (float*)d_out;

  hipMemsetAsync(ws + 25600000, 0, 100096, stream);  // ovf_cnt + gcursor
  k_pb<<<GBLK + FBLK + 193, 256, 0, stream>>>(
      src, dst, feat, Ws0, Wn0, Ws1, Wn1, gcursor, binbuf, ovf_cnt, ovf,
      (uint*)fbf, (uint*)hw, wp0, wp1);
  k_agg0<<<NBIN, 256, 0, stream>>>((const uint4*)fbf, binbuf, gcursor, ovf_cnt,
                                   ovf, (uint4*)hbuf);
  k_gemm<<<GBLK, 256, 0, stream>>>(fbf, hbuf, (const short8*)wp0,
                                   (const short8*)wp1, b0, b1, hw, out);
  k_agg1<<<NBIN, 256, 0, stream>>>((const uint4*)hw, binbuf, gcursor, ovf_cnt,
                                   ovf, out);
}

// Round 5
// 272.174 us; speedup vs baseline: 1.3324x; 1.1061x over previous
//
#include <hip/hip_runtime.h>

#define N_NODES 100000
#define N_EDGES 1600000
#define CAP 60         // per-node bucket capacity, mult. of 12 (Poisson(16): P(deg>60)~1e-16)
#define OVF_CAP 8192
#define GBLK 782       // ceil(100000/128) gemm blocks; also bin blocks (2048 edges)
#define NBIN 1563      // ceil(100000/64): fine bin = dst>>6 (one agg block per bin)
#define NCB 98         // ceil(100000/1024): coarse bin = dst>>10
#define CCAP 17408     // Poisson(16384) + 8 sigma
#define BINCAP2 1280   // Poisson(1024) + 8 sigma
#define FBLK 12500     // feat cvt blocks (float4: 3.2M threads)
#define ZROW 100000    // zero row index (padding gathers)

typedef unsigned int uint;
typedef unsigned short ushort;
typedef __attribute__((ext_vector_type(8))) short short8;  // 8 bf16 (4 VGPRs)
typedef __attribute__((ext_vector_type(4))) float f32x4;   // 4 fp32

__device__ __forceinline__ ushort f2bf(float f) {
  uint x = __float_as_uint(f);
  x += 0x7fffu + ((x >> 16) & 1u);  // round-to-nearest-even
  return (ushort)(x >> 16);
}
__device__ __forceinline__ float bflo(uint u) {
  return __uint_as_float(u << 16);
}
__device__ __forceinline__ float bfhi(uint u) {
  return __uint_as_float(u & 0xffff0000u);
}
// low/high 4 floats of a uint4 (8 bf16)
__device__ __forceinline__ f32x4 uplo(uint4 u) {
  return (f32x4){bflo(u.x), bfhi(u.x), bflo(u.y), bfhi(u.y)};
}
__device__ __forceinline__ f32x4 uphi(uint4 u) {
  return (f32x4){bflo(u.z), bfhi(u.z), bflo(u.w), bfhi(u.w)};
}

// ---------------- fused: COARSE edge binning + feat cvt + weight packing ---
// Blocks [0,782): bin 2048 edges into 98 coarse (1024-node) segments.
// Each block's entries per coarse bin get CONSECUTIVE ranks -> ~84B write
// runs (write amplification ~1.5x vs 9x with 1563 fine segments).
// Cursors are DENSE (padding to 1 line/counter measured SLOWER: sweep
// locality of consecutive-bin atomics beats contention relief).
// Blocks [782,13282): feat f32->bf16 (float4). Then 192 wp blocks + zero rows.
__global__ __launch_bounds__(256) void k_pb(
    const int* __restrict__ src, const int* __restrict__ dst,
    const float* __restrict__ feat, const float* __restrict__ Ws0,
    const float* __restrict__ Wn0, const float* __restrict__ Ws1,
    const float* __restrict__ Wn1, uint* __restrict__ ccur,
    uint* __restrict__ coarse, int* __restrict__ ovf_cnt,
    int* __restrict__ ovf, uint* __restrict__ fbfu, uint* __restrict__ hwu,
    ushort* __restrict__ wp0, ushort* __restrict__ wp1) {
  __shared__ uint hist[NCB];  // counts, then bases (overwritten in place)
  int b = blockIdx.x;
  int tid = threadIdx.x;
  if (b < GBLK) {
    if (tid < NCB) hist[tid] = 0;
    __syncthreads();
    int e0 = b * 2048;
    uint val[8], bn[8], rk[8];
    int vld[8];
#pragma unroll
    for (int it = 0; it < 8; ++it) {
      int e = e0 + it * 256 + tid;
      vld[it] = (e < N_EDGES);
      if (vld[it]) {
        uint s = (uint)src[e];
        uint d = (uint)dst[e];
        bn[it] = d >> 10;
        rk[it] = atomicAdd(&hist[bn[it]], 1u);
        val[it] = s | ((d & 1023u) << 17);  // 27 bits
      }
    }
    __syncthreads();
    if (tid < NCB) {
      uint h = hist[tid];
      hist[tid] = h ? atomicAdd(&ccur[tid], h) : 0u;  // count -> base
    }
    __syncthreads();
#pragma unroll
    for (int it = 0; it < 8; ++it) {
      if (!vld[it]) continue;
      uint p = hist[bn[it]] + rk[it];
      if (p < CCAP) {
        coarse[(size_t)bn[it] * CCAP + p] = val[it];
      } else {  // ~never: segment overflow -> ovf, NOT counted (bit30=0)
        int o = atomicAdd(ovf_cnt, 1);
        if (o < OVF_CAP) {
          ovf[2 * o] = (int)(val[it] & 0x1FFFFu);
          ovf[2 * o + 1] = (int)(bn[it] * 1024 + (val[it] >> 17));
        }
      }
    }
    return;
  }
  if (b < GBLK + FBLK) {  // feat conversion: float4 in, uint2 (4 bf16) out
    int i = (b - GBLK) * 256 + tid;
    float4 v = reinterpret_cast<const float4*>(feat)[i];
    uint2 o;
    o.x = (uint)f2bf(v.x) | ((uint)f2bf(v.y) << 16);
    o.y = (uint)f2bf(v.z) | ((uint)f2bf(v.w) << 16);
    reinterpret_cast<uint2*>(fbfu)[i] = o;
    return;
  }
  int wb = b - GBLK - FBLK;
  if (wb >= 192) {  // zero padding rows fbf[100000], hw[100000]
    if (tid < 64) fbfu[ZROW * 64 + tid] = 0;
    else if (tid < 96) hwu[ZROW * 32 + (tid - 64)] = 0;
    return;
  }
  // B-frag layout (16x16x32 bf16): lane = 16q+c holds B[k=8q+j][n=16t+c].
  int idx = wb * 256 + tid;  // 49152 = 32768 + 16384
  if (idx < 32768) {
    int k = idx >> 7, n = idx & 127;
    float v = (k < 128) ? Ws0[k * 128 + n] : Wn0[(k - 128) * 128 + n];
    int s = k >> 5, q = (k >> 3) & 3, j = k & 7;
    int t = n >> 4, c = n & 15;
    wp0[(((s * 8 + t) * 64) + (q * 16 + c)) * 8 + j] = f2bf(v);
  } else {
    int i2 = idx - 32768;
    int k = i2 >> 7, n = i2 & 127;
    float v = (n < 64) ? Wn1[k * 64 + n] : Ws1[k * 64 + (n - 64)];
    int s = k >> 5, q = (k >> 3) & 3, j = k & 7;
    int t = n >> 4, c = n & 15;
    wp1[(((s * 8 + t) * 64) + (q * 16 + c)) * 8 + j] = f2bf(v);
  }
}

// ---------------- pass B: coarse -> fine binning ---------------------------
// 16 blocks per coarse bin; each scans 1/16 of the segment (coalesced reads)
// and scatters into the coarse bin's 16 fine (64-node) segments. Only 16
// co-scheduled writer blocks per fine segment -> low write amplification.
__global__ __launch_bounds__(256) void k_fb(
    const uint* __restrict__ coarse, const uint* __restrict__ ccur,
    uint* __restrict__ gcursor, int* __restrict__ ovf_cnt,
    int* __restrict__ ovf, uint* __restrict__ binbuf) {
  __shared__ uint hist[16];
  int blk = blockIdx.x;
  int tid = threadIdx.x;
  int cb = blk >> 4, q = blk & 15;
  if (tid < 16) hist[tid] = 0;
  __syncthreads();
  int ne = min((int)ccur[cb], CCAP);
  int lo = (q * ne) >> 4, hi = ((q + 1) * ne) >> 4;  // <= 1088 entries
  uint val[5], rk[5];
  int bnv[5], vld[5];
#pragma unroll
  for (int it = 0; it < 5; ++it) {
    int i = lo + it * 256 + tid;
    vld[it] = (i < hi);
    if (vld[it]) {
      uint v = coarse[(size_t)cb * CCAP + i];
      uint d10 = v >> 17;
      int f = (int)(d10 >> 6);  // 0..15
      rk[it] = atomicAdd(&hist[f], 1u);
      bnv[it] = f;
      val[it] = (v & 0x1FFFFu) | ((d10 & 63u) << 17);
    }
  }
  __syncthreads();
  if (tid < 16) {
    uint h = hist[tid];
    hist[tid] = h ? atomicAdd(&gcursor[cb * 16 + tid], h) : 0u;
  }
  __syncthreads();
#pragma unroll
  for (int it = 0; it < 5; ++it) {
    if (!vld[it]) continue;
    uint p = hist[bnv[it]] + rk[it];
    int fine = cb * 16 + bnv[it];
    if (p < BINCAP2) {
      binbuf[(size_t)fine * BINCAP2 + p] = val[it];
    } else {  // ~never: fine overflow -> ovf, NOT counted (bit30=0)
      int o = atomicAdd(ovf_cnt, 1);
      if (o < OVF_CAP) {
        ovf[2 * o] = (int)(val[it] & 0x1FFFFu);
        ovf[2 * o + 1] = fine * 64 + (int)(val[it] >> 17);
      }
    }
  }
}

// ---------------- layer-0 aggregation (LDS bucket): 64 nodes/block ---------
// Phase 1: scan own bin's binbuf segment (~1024 edges, no filtering),
// scatter src ids into a 15KB LDS bucket pre-filled with ZROW.
// Phase 2: 16 lanes per node own the 256B row; 12-deep unconditional gather
// batches (12 dwordx4 in flight/lane, tail lanes hit the zero row).
__global__ __launch_bounds__(256) void k_agg0(
    const uint4* __restrict__ fbf4, const uint* __restrict__ binbuf,
    const uint* __restrict__ gcursor, int* __restrict__ ovf_cnt,
    int* __restrict__ ovf, uint4* __restrict__ agg4) {
  __shared__ __attribute__((aligned(16))) int lbkt[64 * CAP];
  __shared__ uint lcnt[64];
  int bb = blockIdx.x;
  int tid = threadIdx.x;
  if (tid < 64) lcnt[tid] = 0;
#pragma unroll
  for (int i = tid; i < 64 * CAP; i += 256) lbkt[i] = ZROW;
  __syncthreads();
  int ne = min((int)gcursor[bb], BINCAP2);
  for (int i = tid; i < ne; i += 256) {
    uint v = binbuf[(size_t)bb * BINCAP2 + i];
    int ldl = (int)(v >> 17);
    uint pos = atomicAdd(&lcnt[ldl], 1u);
    if (pos < CAP) {
      lbkt[ldl * CAP + pos] = (int)(v & 0x1FFFFu);
    } else {  // ~never: bucket spill -> ovf, already counted (bit30=1)
      int o = atomicAdd(ovf_cnt, 1);
      if (o < OVF_CAP) {
        ovf[2 * o] = (int)(v & 0x1FFFFu);
        ovf[2 * o + 1] = (bb * 64 + ldl) | (1 << 30);
      }
    }
  }
  __syncthreads();
  int g = tid >> 4, li = tid & 15;
  const int4* lb4 = reinterpret_cast<const int4*>(lbkt);
  int oc = min(*ovf_cnt, OVF_CAP);
#pragma unroll
  for (int p = 0; p < 4; ++p) {
    int nl = p * 16 + g;
    int n = bb * 64 + nl;
    int c = (int)lcnt[nl];
    int kb = min(c, CAP);
    f32x4 accA = (f32x4){0.f, 0.f, 0.f, 0.f};
    f32x4 accB = (f32x4){0.f, 0.f, 0.f, 0.f};
    for (int j = 0; j < kb; j += 12) {
      int4 ia = lb4[nl * 15 + (j >> 2)];
      int4 ib = lb4[nl * 15 + (j >> 2) + 1];
      int4 ic = lb4[nl * 15 + (j >> 2) + 2];
      uint4 u0 = fbf4[(size_t)ia.x * 16 + li];
      uint4 u1 = fbf4[(size_t)ia.y * 16 + li];
      uint4 u2 = fbf4[(size_t)ia.z * 16 + li];
      uint4 u3 = fbf4[(size_t)ia.w * 16 + li];
      uint4 u4 = fbf4[(size_t)ib.x * 16 + li];
      uint4 u5 = fbf4[(size_t)ib.y * 16 + li];
      uint4 u6 = fbf4[(size_t)ib.z * 16 + li];
      uint4 u7 = fbf4[(size_t)ib.w * 16 + li];
      uint4 u8 = fbf4[(size_t)ic.x * 16 + li];
      uint4 u9 = fbf4[(size_t)ic.y * 16 + li];
      uint4 ua = fbf4[(size_t)ic.z * 16 + li];
      uint4 ub = fbf4[(size_t)ic.w * 16 + li];
      accA += uplo(u0); accB += uphi(u0);
      accA += uplo(u1); accB += uphi(u1);
      accA += uplo(u2); accB += uphi(u2);
      accA += uplo(u3); accB += uphi(u3);
      accA += uplo(u4); accB += uphi(u4);
      accA += uplo(u5); accB += uphi(u5);
      accA += uplo(u6); accB += uphi(u6);
      accA += uplo(u7); accB += uphi(u7);
      accA += uplo(u8); accB += uphi(u8);
      accA += uplo(u9); accB += uphi(u9);
      accA += uplo(ua); accB += uphi(ua);
      accA += uplo(ub); accB += uphi(ub);
    }
    for (int i = 0; i < oc; ++i) {  // cold fallback path
      int df = ovf[2 * i + 1];
      if ((df & 0x1FFFF) == n) {
        uint4 u = fbf4[(size_t)ovf[2 * i] * 16 + li];
        accA += uplo(u);
        accB += uphi(u);
        c += ((df >> 30) & 1) ^ 1;
      }
    }
    float inv = 1.f / (float)max(c, 1);
    accA *= inv;
    accB *= inv;
    if (n < N_NODES) {
      uint4 o;
      o.x = (uint)f2bf(accA.x) | ((uint)f2bf(accA.y) << 16);
      o.y = (uint)f2bf(accA.z) | ((uint)f2bf(accA.w) << 16);
      o.z = (uint)f2bf(accB.x) | ((uint)f2bf(accB.y) << 16);
      o.w = (uint)f2bf(accB.z) | ((uint)f2bf(accB.w) << 16);
      agg4[(size_t)n * 16 + li] = o;
    }
  }
}

// ---------------- fused MFMA GEMM: h-tile in LDS, no h round-trip ----------
// Phase 1: h = relu([fbf|agg] @ Wp0 + b0) -> 32KB LDS tile (col-XOR swizzle).
// Phase 2: [hw | out] = h_tile @ Wp1. B-frags read directly from global
// (wp0/wp1 = 96KB, L2-hot across all blocks) -> LDS stays 32KB, 5 blocks/CU.
__global__ __launch_bounds__(256) void k_gemm(
    const ushort* __restrict__ fbf, const ushort* __restrict__ aggb,
    const short8* __restrict__ wp0f, const short8* __restrict__ wp1f,
    const float* __restrict__ b0, const float* __restrict__ b1,
    ushort* __restrict__ hw, float* __restrict__ out) {
  __shared__ ushort htile[128 * 128];  // 32KB; idx = r*128 + (c ^ ((r&15)*8))
  int tid = threadIdx.x;
  int lane = tid & 63, w = tid >> 6;
  int quad = lane >> 4, lm = lane & 15;
  int rl0 = (w >> 1) * 64;            // block-local row base of this wave
  int mw = blockIdx.x * 128 + rl0;
  int tgb = (w & 1) * 4;

  f32x4 acc[4][4];
#pragma unroll
  for (int rt = 0; rt < 4; ++rt)
#pragma unroll
    for (int ct = 0; ct < 4; ++ct) acc[rt][ct] = (f32x4){0.f, 0.f, 0.f, 0.f};
  short8 az = {0, 0, 0, 0, 0, 0, 0, 0};

#pragma unroll
  for (int s = 0; s < 8; ++s) {  // K=256 over [fbf | agg]
    const ushort* bsrc = (s < 4) ? fbf : aggb;
    int koff = (s & 3) * 32 + quad * 8;
    short8 a[4];
#pragma unroll
    for (int rt = 0; rt < 4; ++rt) {
      int row = mw + rt * 16 + lm;
      a[rt] = (row < N_NODES)
                  ? *reinterpret_cast<const short8*>(bsrc + (size_t)row * 128 + koff)
                  : az;
    }
#pragma unroll
    for (int ct = 0; ct < 4; ++ct) {
      short8 b = wp0f[(s * 8 + tgb + ct) * 64 + lane];
#pragma unroll
      for (int rt = 0; rt < 4; ++rt)
        acc[rt][ct] =
            __builtin_amdgcn_mfma_f32_16x16x32_bf16(a[rt], b, acc[rt][ct], 0, 0, 0);
    }
  }

  {  // epilogue 1 -> LDS h-tile (bias + relu + bf16); tail rows zeroed
    float bv[4];
#pragma unroll
    for (int ct = 0; ct < 4; ++ct) bv[ct] = b0[(tgb + ct) * 16 + lm];
#pragma unroll
    for (int rt = 0; rt < 4; ++rt)
#pragma unroll
      for (int ct = 0; ct < 4; ++ct)
#pragma unroll
        for (int i = 0; i < 4; ++i) {
          int r = rl0 + rt * 16 + quad * 4 + i;
          float v = (blockIdx.x * 128 + r < N_NODES)
                        ? fmaxf(acc[rt][ct][i] + bv[ct], 0.f)
                        : 0.f;
          int col = (tgb + ct) * 16 + lm;
          htile[r * 128 + (col ^ ((r & 15) * 8))] = f2bf(v);
        }
  }
  __syncthreads();

#pragma unroll
  for (int rt = 0; rt < 4; ++rt)
#pragma unroll
    for (int ct = 0; ct < 4; ++ct) acc[rt][ct] = (f32x4){0.f, 0.f, 0.f, 0.f};

#pragma unroll
  for (int s = 0; s < 4; ++s) {  // K=128 from h-tile
    int koff = s * 32 + quad * 8;
    short8 a[4];
#pragma unroll
    for (int rt = 0; rt < 4; ++rt) {
      int r = rl0 + rt * 16 + lm;
      a[rt] = *reinterpret_cast<const short8*>(
          &htile[r * 128 + (koff ^ ((r & 15) * 8))]);
    }
#pragma unroll
    for (int ct = 0; ct < 4; ++ct) {
      short8 b = wp1f[(s * 8 + tgb + ct) * 64 + lane];
#pragma unroll
      for (int rt = 0; rt < 4; ++rt)
        acc[rt][ct] =
            __builtin_amdgcn_mfma_f32_16x16x32_bf16(a[rt], b, acc[rt][ct], 0, 0, 0);
    }
  }

  if ((w & 1) == 0) {  // cols 0..63 -> hw = h@Wn1 (bf16)
#pragma unroll
    for (int rt = 0; rt < 4; ++rt)
#pragma unroll
      for (int ct = 0; ct < 4; ++ct)
#pragma unroll
        for (int i = 0; i < 4; ++i) {
          int row = mw + rt * 16 + quad * 4 + i;
          if (row < N_NODES)
            hw[(size_t)row * 64 + ct * 16 + lm] = f2bf(acc[rt][ct][i]);
        }
  } else {  // cols 64..127 -> out = h@Ws1 + b1 (f32)
    float bv[4];
#pragma unroll
    for (int ct = 0; ct < 4; ++ct) bv[ct] = b1[ct * 16 + lm];
#pragma unroll
    for (int rt = 0; rt < 4; ++rt)
#pragma unroll
      for (int ct = 0; ct < 4; ++ct)
#pragma unroll
        for (int i = 0; i < 4; ++i) {
          int row = mw + rt * 16 + quad * 4 + i;
          if (row < N_NODES)
            out[(size_t)row * 64 + ct * 16 + lm] = acc[rt][ct][i] + bv[ct];
        }
  }
}

// ---------------- layer-1 aggregation (LDS bucket): out[n] += mean ---------
// Same structure as k_agg0; 8 lanes per node own the 128B hw row.
__global__ __launch_bounds__(256) void k_agg1(
    const uint4* __restrict__ hw4, const uint* __restrict__ binbuf,
    const uint* __restrict__ gcursor, int* __restrict__ ovf_cnt,
    int* __restrict__ ovf, float* __restrict__ out) {
  __shared__ __attribute__((aligned(16))) int lbkt[64 * CAP];
  __shared__ uint lcnt[64];
  int bb = blockIdx.x;
  int tid = threadIdx.x;
  if (tid < 64) lcnt[tid] = 0;
#pragma unroll
  for (int i = tid; i < 64 * CAP; i += 256) lbkt[i] = ZROW;
  __syncthreads();
  int ne = min((int)gcursor[bb], BINCAP2);
  for (int i = tid; i < ne; i += 256) {
    uint v = binbuf[(size_t)bb * BINCAP2 + i];
    int ldl = (int)(v >> 17);
    uint pos = atomicAdd(&lcnt[ldl], 1u);
    if (pos < CAP) lbkt[ldl * CAP + pos] = (int)(v & 0x1FFFFu);
    // bucket spill already recorded in ovf by k_agg0's pass (bit30=1)
  }
  __syncthreads();
  int g = tid >> 3, li = tid & 7;
  const int4* lb4 = reinterpret_cast<const int4*>(lbkt);
  int oc = min(*ovf_cnt, OVF_CAP);
#pragma unroll
  for (int p = 0; p < 2; ++p) {
    int nl = p * 32 + g;
    int n = bb * 64 + nl;
    int c = (int)lcnt[nl];
    int kb = min(c, CAP);
    f32x4 accA = (f32x4){0.f, 0.f, 0.f, 0.f};
    f32x4 accB = (f32x4){0.f, 0.f, 0.f, 0.f};
    for (int j = 0; j < kb; j += 12) {
      int4 ia = lb4[nl * 15 + (j >> 2)];
      int4 ib = lb4[nl * 15 + (j >> 2) + 1];
      int4 ic = lb4[nl * 15 + (j >> 2) + 2];
      uint4 u0 = hw4[(size_t)ia.x * 8 + li];
      uint4 u1 = hw4[(size_t)ia.y * 8 + li];
      uint4 u2 = hw4[(size_t)ia.z * 8 + li];
      uint4 u3 = hw4[(size_t)ia.w * 8 + li];
      uint4 u4 = hw4[(size_t)ib.x * 8 + li];
      uint4 u5 = hw4[(size_t)ib.y * 8 + li];
      uint4 u6 = hw4[(size_t)ib.z * 8 + li];
      uint4 u7 = hw4[(size_t)ib.w * 8 + li];
      uint4 u8 = hw4[(size_t)ic.x * 8 + li];
      uint4 u9 = hw4[(size_t)ic.y * 8 + li];
      uint4 ua = hw4[(size_t)ic.z * 8 + li];
      uint4 ub = hw4[(size_t)ic.w * 8 + li];
      accA += uplo(u0); accB += uphi(u0);
      accA += uplo(u1); accB += uphi(u1);
      accA += uplo(u2); accB += uphi(u2);
      accA += uplo(u3); accB += uphi(u3);
      accA += uplo(u4); accB += uphi(u4);
      accA += uplo(u5); accB += uphi(u5);
      accA += uplo(u6); accB += uphi(u6);
      accA += uplo(u7); accB += uphi(u7);
      accA += uplo(u8); accB += uphi(u8);
      accA += uplo(u9); accB += uphi(u9);
      accA += uplo(ua); accB += uphi(ua);
      accA += uplo(ub); accB += uphi(ub);
    }
    for (int i = 0; i < oc; ++i) {  // cold fallback path
      int df = ovf[2 * i + 1];
      if ((df & 0x1FFFF) == n) {
        uint4 u = hw4[(size_t)ovf[2 * i] * 8 + li];
        accA += uplo(u);
        accB += uphi(u);
        c += ((df >> 30) & 1) ^ 1;
      }
    }
    if (n < N_NODES) {
      float inv = 1.f / (float)max(c, 1);
      float* op = out + (size_t)n * 64 + li * 8;
      float4 c0 = *reinterpret_cast<float4*>(op);
      float4 c1 = *reinterpret_cast<float4*>(op + 4);
      c0.x += accA.x * inv;
      c0.y += accA.y * inv;
      c0.z += accA.z * inv;
      c0.w += accA.w * inv;
      c1.x += accB.x * inv;
      c1.y += accB.y * inv;
      c1.z += accB.z * inv;
      c1.w += accB.w * inv;
      *reinterpret_cast<float4*>(op) = c0;
      *reinterpret_cast<float4*>(op + 4) = c1;
    }
  }
}

extern "C" void kernel_launch(void* const* d_in, const int* in_sizes, int n_in,
                              void* d_out, int out_size, void* d_ws,
                              size_t ws_size, hipStream_t stream) {
  const float* feat = (const float*)d_in[0];
  const int* src = (const int*)d_in[1];
  const int* dst = (const int*)d_in[2];
  const float* Ws0 = (const float*)d_in[3];
  const float* Wn0 = (const float*)d_in[4];
  const float* b0 = (const float*)d_in[5];
  const float* Ws1 = (const float*)d_in[6];
  const float* Wn1 = (const float*)d_in[7];
  const float* b1 = (const float*)d_in[8];
  char* ws = (char*)d_ws;

  // Workspace (72.2 MB <= 77.2 MB proven):
  //   hbuf    @ 0          : 25,600,000  (coarse binbuf during k_pb/k_fb,
  //                                       then bf16 agg0 out for k_gemm)
  //   ovf_cnt @ 25,600,000 :         64
  //   gcursor @ 25,600,064 :      6,272  (1568 fine cursors, dense)
  //   ccur    @ 25,606,336 :        448  (98 coarse cursors, dense)
  //   ovf     @ 25,606,784 :     65,536
  //   binbuf  @ 25,672,320 :  8,002,560  (1563 x 1280 packed edges)
  //   feat_bf @ 33,674,880 : 25,600,256  (bf16 + zero row)
  //   hw      @ 59,275,136 : 12,800,128  (bf16 h@Wn1 + zero row)
  //   wp0     @ 72,075,264 :     65,536
  //   wp1     @ 72,140,800 :     32,768
  ushort* hbuf = (ushort*)(ws);
  uint* coarse = (uint*)(ws);  // aliases hbuf (dead before agg0 writes)
  int* ovf_cnt = (int*)(ws + 25600000);
  uint* gcursor = (uint*)(ws + 25600064);
  uint* ccur = (uint*)(ws + 25606336);
  int* ovf = (int*)(ws + 25606784);
  uint* binbuf = (uint*)(ws + 25672320);
  ushort* fbf = (ushort*)(ws + 33674880);
  ushort* hw = (ushort*)(ws + 59275136);
  ushort* wp0 = (ushort*)(ws + 72075264);
  ushort* wp1 = (ushort*)(ws + 72140800);
  float* out = (float*)d_out;

  hipMemsetAsync(ws + 25600000, 0, 6784, stream);  // ovf_cnt+gcursor+ccur
  k_pb<<<GBLK + FBLK + 193, 256, 0, stream>>>(
      src, dst, feat, Ws0, Wn0, Ws1, Wn1, ccur, coarse, ovf_cnt, ovf,
      (uint*)fbf, (uint*)hw, wp0, wp1);
  k_fb<<<NCB * 16, 256, 0, stream>>>(coarse, ccur, gcursor, ovf_cnt, ovf,
                                     binbuf);
  k_agg0<<<NBIN, 256, 0, stream>>>((const uint4*)fbf, binbuf, gcursor, ovf_cnt,
                                   ovf, (uint4*)hbuf);
  k_gemm<<<GBLK, 256, 0, stream>>>(fbf, hbuf, (const short8*)wp0,
                                   (const short8*)wp1, b0, b1, hw, out);
  k_agg1<<<NBIN, 256, 0, stream>>>((const uint4*)hw, binbuf, gcursor, ovf_cnt,
                                   ovf, out);
}